// Round 2
// baseline (323.714 us; speedup 1.0000x reference)
//
#include <hip/hip_runtime.h>
#include <hip/hip_bf16.h>

#define FEAT 256

typedef __attribute__((ext_vector_type(8))) short short8;
typedef __attribute__((ext_vector_type(4))) float floatx4;

__device__ __forceinline__ short f2bf(float f) {
    __hip_bfloat16 h = __float2bfloat16(f);   // RTNE; compiler packs into v_cvt_pk_bf16_f32
    return __builtin_bit_cast(short, h);
}

// Block = 4 waves. Block owns a 64-column quarter (cq) and grid-strides over
// 64-row tiles; wave w handles rows [rb + 16w, rb + 16w + 16).
// gamma (bf16) staged once per block in LDS, FRAGMENT-ORDERED:
//   chunk(nt,ks,grp,l15) = ((nt*8+ks)*4 + grp)*16 + l15   (16 B per chunk)
// so a wave's B-fragment read is ds_read_b128 at uniform base + lane*16,
// conflict-free, with compile-time immediate offsets per (nt,ks).
__global__ __launch_bounds__(256, 4) void gdn_kernel(
    const float* __restrict__ x,
    const float* __restrict__ beta,
    const float* __restrict__ gamma,
    float* __restrict__ out,
    int batch)
{
    __shared__ short8 ldsB[2048];   // 32 KiB

    const int tid  = threadIdx.x;
    const int lane = tid & 63;
    const int wave = tid >> 6;
    const int l15  = lane & 15;
    const int grp  = lane >> 4;

    const int rts     = gridDim.x >> 2;        // row-tile stride (256 for grid 1024)
    const int cq      = blockIdx.x / rts;      // 0..3 column quarter
    const int rt0     = blockIdx.x % rts;      // same-rt blocks are rts apart -> same XCD (rts%8==0)
    const int colbase = cq * 64;

    // ---- stage gamma -> LDS (bf16, fragment order). 2048 chunks / 256 thr = 8 each.
    #pragma unroll
    for (int t = 0; t < 8; ++t) {
        const int ch   = tid + t * 256;
        const int c_l  = ch & 15;
        const int c_g  = (ch >> 4) & 3;
        const int c_ks = (ch >> 6) & 7;
        const int c_nt = ch >> 9;
        const int col  = colbase + c_nt * 16 + c_l;
        const int k0   = c_ks * 32 + c_g * 8;   // same k-hat map as A below (self-consistent)
        short8 b;
        #pragma unroll
        for (int i = 0; i < 8; ++i)
            b[i] = f2bf(gamma[(size_t)(k0 + i) * FEAT + col]);
        ldsB[ch] = b;
    }

    float bc[4];
    #pragma unroll
    for (int nt = 0; nt < 4; ++nt)
        bc[nt] = fmaxf(beta[colbase + nt * 16 + l15], 1e-6f);

    __syncthreads();   // LDS is read-only after this; no barriers in the loop

    const short8* Blane = ldsB + grp * 16 + l15;

    const int nrt = batch >> 6;                 // 64-row tiles
    for (int rt = rt0; rt < nrt; rt += rts) {
        const int rb = (rt << 6) + wave * 16;   // this wave's 16 rows

        // ---- A fragments: x^2 as bf16. Lane reads row (rb+l15),
        // k = ks*32 + grp*8 + i; lanes (l15 fixed, grp 0..3) cover 128 B contiguous.
        short8 Af[8];
        const float* xrow = x + (size_t)(rb + l15) * FEAT + grp * 8;
        #pragma unroll
        for (int ks = 0; ks < 8; ++ks) {
            const floatx4* p = (const floatx4*)(xrow + ks * 32);
            floatx4 v0 = p[0];
            floatx4 v1 = p[1];
            short8 a;
            #pragma unroll
            for (int i = 0; i < 4; ++i) {
                a[i]     = f2bf(v0[i] * v0[i]);
                a[4 + i] = f2bf(v1[i] * v1[i]);
            }
            Af[ks] = a;
        }

        // ---- MFMA over K=256; B streamed from LDS (linear, conflict-free)
        floatx4 acc[4] = {{0.f,0.f,0.f,0.f},{0.f,0.f,0.f,0.f},
                          {0.f,0.f,0.f,0.f},{0.f,0.f,0.f,0.f}};
        #pragma unroll
        for (int ks = 0; ks < 8; ++ks) {
            #pragma unroll
            for (int nt = 0; nt < 4; ++nt) {
                acc[nt] = __builtin_amdgcn_mfma_f32_16x16x32_bf16(
                    Af[ks], Blane[(nt * 8 + ks) * 64], acc[nt], 0, 0, 0);
            }
        }

        // ---- Epilogue: y = x * rsqrt(acc + beta_c)
        // C/D layout: col = lane&15, row = (lane>>4)*4 + reg. x reload is L1-hot.
        #pragma unroll
        for (int nt = 0; nt < 4; ++nt) {
            const int col = colbase + nt * 16 + l15;
            #pragma unroll
            for (int r = 0; r < 4; ++r) {
                const int row = rb + grp * 4 + r;
                const size_t idx = (size_t)row * FEAT + col;
                out[idx] = x[idx] * rsqrtf(acc[nt][r] + bc[nt]);
            }
        }
    }
}

extern "C" void kernel_launch(void* const* d_in, const int* in_sizes, int n_in,
                              void* d_out, int out_size, void* d_ws, size_t ws_size,
                              hipStream_t stream) {
    const float* x     = (const float*)d_in[0];
    const float* beta  = (const float*)d_in[1];
    const float* gamma = (const float*)d_in[2];
    float* out = (float*)d_out;

    const int batch = in_sizes[0] / FEAT;   // 262144

    dim3 grid(1024);    // 4 col-quarters x 256 row-tile streams; 4 blocks/CU resident
    dim3 block(256);
    hipLaunchKernelGGL(gdn_kernel, grid, block, 0, stream,
                       x, beta, gamma, out, batch);
}